// Round 10
// baseline (2471.521 us; speedup 1.0000x reference)
//
#include <hip/hip_runtime.h>
#include <hip/hip_bf16.h>

#define HID 128
#define BSH 6            // 64 nodes per bucket
#define MAXBUCK 2048     // >= ceil(n/64); n=100000 -> 1563

__device__ __forceinline__ float b2f(unsigned short u) {
    union { unsigned i; float f; } v; v.i = ((unsigned)u) << 16; return v.f;
}
__device__ __forceinline__ unsigned short f2b(float f) {
    unsigned u = __float_as_uint(f);
    return (unsigned short)((u + 0x7fffu + ((u >> 16) & 1u)) >> 16);  // RNE
}

// ---------------- zero bucket counters ----------------
__global__ void zero_kernel(unsigned* __restrict__ p, int n) {
    int i = blockIdx.x * blockDim.x + threadIdx.x;
    if (i < n) p[i] = 0u;
}

// ---------------- K1: bucket histogram (LDS-aggregated) ----------------
__global__ __launch_bounds__(256) void bincount_kernel(const int* __restrict__ ei,
                                                       unsigned* __restrict__ bcount,
                                                       int E, int n, int nbuck) {
    __shared__ unsigned hist[MAXBUCK];
    for (int i = threadIdx.x; i < nbuck; i += 256) hist[i] = 0u;
    __syncthreads();
    int i = blockIdx.x * 256 + threadIdx.x, stride = gridDim.x * 256;
    for (; i < E; i += stride) {
        int dst = ei[(size_t)E + i];
        if ((unsigned)dst < (unsigned)n) atomicAdd(&hist[dst >> BSH], 1u);
    }
    __syncthreads();
    for (int b = threadIdx.x; b < nbuck; b += 256) {
        unsigned c = hist[b];
        if (c) atomicAdd(&bcount[b], c);
    }
}

// ---------------- K2: scan of bucket counts (single block) ----------------
__global__ __launch_bounds__(1024) void bscan_kernel(const unsigned* __restrict__ bcount,
                                                     unsigned* __restrict__ boff,
                                                     unsigned* __restrict__ bwoff,
                                                     int nbuck) {
    __shared__ unsigned sums[1024];
    int t = threadIdx.x;
    int chunk = (nbuck + 1023) >> 10;
    int beg = min(t * chunk, nbuck), end = min(beg + chunk, nbuck);
    unsigned local = 0;
    for (int i = beg; i < end; ++i) local += bcount[i];
    sums[t] = local;
    __syncthreads();
    for (int d = 1; d < 1024; d <<= 1) {
        unsigned v = (t >= d) ? sums[t - d] : 0u;
        __syncthreads();
        sums[t] += v;
        __syncthreads();
    }
    unsigned run = (t > 0) ? sums[t - 1] : 0u;
    for (int i = beg; i < end; ++i) { boff[i] = run; bwoff[i] = run; run += bcount[i]; }
    if (t == 1023) boff[nbuck] = sums[1023];
}

// ---------------- K3 (fused): binscatter (blocks 0..nsb-1) + gemm (rest) ----------------
// binned[pos] = (dst&63)<<20 | src ; gemm: hp = (x+h_cur)@W[:,0:128] bf16 flat [n][128]
__global__ __launch_bounds__(256) void phase3_kernel(const int* __restrict__ ei,
                                                     unsigned* __restrict__ bwoff,
                                                     unsigned* __restrict__ binned,
                                                     const float* __restrict__ x,
                                                     const float* __restrict__ hc,
                                                     const float* __restrict__ W,
                                                     unsigned short* __restrict__ hp,
                                                     int E, int n, int nbuck, int nsb) {
    __shared__ union {
        struct { unsigned hist[MAXBUCK]; unsigned base[MAXBUCK]; } bs;
        float A[64 * 132];
    } sm;

    if (blockIdx.x < nsb) {
        // ---- binscatter body ----
        int chunk = (E + nsb - 1) / nsb;
        int beg = blockIdx.x * chunk, end = min(E, beg + chunk);
        for (int i = threadIdx.x; i < nbuck; i += 256) sm.bs.hist[i] = 0u;
        __syncthreads();
        for (int i = beg + threadIdx.x; i < end; i += 256) {
            int dst = ei[(size_t)E + i];
            if ((unsigned)dst < (unsigned)n) atomicAdd(&sm.bs.hist[dst >> BSH], 1u);
        }
        __syncthreads();
        for (int b = threadIdx.x; b < nbuck; b += 256) {
            unsigned c = sm.bs.hist[b];
            sm.bs.base[b] = c ? atomicAdd(&bwoff[b], c) : 0u;
            sm.bs.hist[b] = 0u;
        }
        __syncthreads();
        for (int i = beg + threadIdx.x; i < end; i += 256) {
            int s = ei[i];
            int dst = ei[(size_t)E + i];
            if ((unsigned)dst >= (unsigned)n) continue;
            unsigned ss = (unsigned)min(max(s, 0), n - 1);
            int b = dst >> BSH;
            unsigned r = atomicAdd(&sm.bs.hist[b], 1u);
            binned[sm.bs.base[b] + r] = ss | ((unsigned)(dst & ((1 << BSH) - 1)) << 20);
        }
    } else {
        // ---- gemm body, flat hp output (unscaled) ----
        int tid = threadIdx.x;
        int r0 = (blockIdx.x - nsb) * 64;

        for (int i = tid; i < 2048; i += 256) {
            int row = i >> 5;
            int c4 = (i & 31) * 4;
            int grow = r0 + row;
            float4 v;
            if (grow < n) {
                float4 a = *(const float4*)(x + (size_t)grow * HID + c4);
                float4 bb = *(const float4*)(hc + (size_t)grow * HID + c4);
                v = make_float4(a.x + bb.x, a.y + bb.y, a.z + bb.z, a.w + bb.w);
            } else {
                v = make_float4(0.f, 0.f, 0.f, 0.f);
            }
            *(float4*)(&sm.A[row * 132 + c4]) = v;
        }
        __syncthreads();

        int cg = tid & 31;
        int c4 = cg * 4;
        int rg = tid >> 5;
        float acc[8][4];
#pragma unroll
        for (int r = 0; r < 8; ++r) {
            acc[r][0] = 0.f; acc[r][1] = 0.f; acc[r][2] = 0.f; acc[r][3] = 0.f;
        }

#pragma unroll 4
        for (int k = 0; k < 128; ++k) {
            float4 w = *(const float4*)(W + (size_t)k * 512 + c4);
#pragma unroll
            for (int r = 0; r < 8; ++r) {
                float a = sm.A[(rg * 8 + r) * 132 + k];
                acc[r][0] += a * w.x;
                acc[r][1] += a * w.y;
                acc[r][2] += a * w.z;
                acc[r][3] += a * w.w;
            }
        }

#pragma unroll
        for (int r = 0; r < 8; ++r) {
            int grow = r0 + rg * 8 + r;
            if (grow < n) {
                unsigned long long pack =
                    (unsigned long long)f2b(acc[r][0]) |
                    ((unsigned long long)f2b(acc[r][1]) << 16) |
                    ((unsigned long long)f2b(acc[r][2]) << 32) |
                    ((unsigned long long)f2b(acc[r][3]) << 48);
                *(unsigned long long*)(hp + (size_t)grow * HID + c4) = pack;
            }
        }
    }
}

// ---------------- K4: per-bucket degree -> dinv ----------------
__global__ __launch_bounds__(256) void degree_kernel(const unsigned* __restrict__ binned,
                                                     const unsigned* __restrict__ boff,
                                                     float* __restrict__ dinv, int n) {
    __shared__ unsigned hist[64];
    int b = blockIdx.x;
    int t = threadIdx.x;
    if (t < 64) hist[t] = 0u;
    __syncthreads();
    unsigned s0 = boff[b], s1 = boff[b + 1];
    for (unsigned j = s0 + t; j < s1; j += 256) atomicAdd(&hist[binned[j] >> 20], 1u);
    __syncthreads();
    if (t < 64) {
        int node = (b << BSH) + t;
        if (node < n) dinv[node] = rsqrtf((float)(hist[t] + 1u));  // +1 self-loop
    }
}

// ---------------- K5: bucket-direct aggregate with LDS f32 accumulator ----------------
// Block = 1 bucket (64 nodes). All 64 lanes process the SAME edge (no divergence):
// lane handles cols {lane, 64+lane} -> LDS banks 2-way (free). 8-deep pipelined.
__global__ __launch_bounds__(256) void agg_direct_kernel(const unsigned* __restrict__ binned,
                                                         const unsigned* __restrict__ boff,
                                                         const float* __restrict__ dinv,
                                                         const unsigned short* __restrict__ hp,
                                                         const float* __restrict__ bias,
                                                         float* __restrict__ out, int n) {
    __shared__ float acc[64 * HID];   // 32 KB
    int b = blockIdx.x;
    int tid = threadIdx.x;
    for (int i = tid; i < 64 * HID; i += 256) acc[i] = 0.f;
    __syncthreads();

    unsigned s0 = boff[b], s1 = boff[b + 1];
    unsigned cnt = s1 - s0;
    int w = tid >> 6, lane = tid & 63;
    unsigned per = (cnt + 3) >> 2;
    unsigned wb = s0 + min((unsigned)(w * per), cnt);
    unsigned we = s0 + min((unsigned)((w + 1) * per), cnt);

    unsigned i = wb;
    for (; i + 8 <= we; i += 8) {
        unsigned e[8];
#pragma unroll
        for (int j = 0; j < 8; ++j) e[j] = binned[i + j];
        float ds[8]; unsigned short va[8], vb[8];
#pragma unroll
        for (int j = 0; j < 8; ++j) ds[j] = dinv[e[j] & 0xFFFFFu];
#pragma unroll
        for (int j = 0; j < 8; ++j) {
            const unsigned short* row = hp + ((size_t)(e[j] & 0xFFFFFu) << 7);
            va[j] = row[lane];
            vb[j] = row[64 + lane];
        }
#pragma unroll
        for (int j = 0; j < 8; ++j) {
            int dl = (int)(e[j] >> 20);
            atomicAdd(&acc[dl * HID + lane], ds[j] * b2f(va[j]));
            atomicAdd(&acc[dl * HID + 64 + lane], ds[j] * b2f(vb[j]));
        }
    }
    if (i < we) {  // masked clamped tail, keeps 8 loads in flight
        unsigned last = we - 1;
        unsigned e[8]; float m[8];
#pragma unroll
        for (int j = 0; j < 8; ++j) {
            unsigned jj = i + j;
            m[j] = (jj < we) ? 1.f : 0.f;
            e[j] = binned[jj < we ? jj : last];
        }
        float ds[8]; unsigned short va[8], vb[8];
#pragma unroll
        for (int j = 0; j < 8; ++j) ds[j] = dinv[e[j] & 0xFFFFFu] * m[j];
#pragma unroll
        for (int j = 0; j < 8; ++j) {
            const unsigned short* row = hp + ((size_t)(e[j] & 0xFFFFFu) << 7);
            va[j] = row[lane];
            vb[j] = row[64 + lane];
        }
#pragma unroll
        for (int j = 0; j < 8; ++j) {
            int dl = (int)(e[j] >> 20);
            atomicAdd(&acc[dl * HID + lane], ds[j] * b2f(va[j]));
            atomicAdd(&acc[dl * HID + 64 + lane], ds[j] * b2f(vb[j]));
        }
    }
    __syncthreads();

    // epilogue: out[node] = dinv_d * (acc + dinv_d * h_d) + bias
    for (int idx = tid; idx < 64 * HID; idx += 256) {
        int ndl = idx >> 7, col = idx & (HID - 1);
        int node = (b << BSH) + ndl;
        if (node < n) {
            float dd = dinv[node];
            float self = dd * b2f(hp[((size_t)node << 7) + col]);
            out[((size_t)node << 7) + col] = dd * (acc[idx] + self) + bias[col];
        }
    }
}

extern "C" void kernel_launch(void* const* d_in, const int* in_sizes, int n_in,
                              void* d_out, int out_size, void* d_ws, size_t ws_size,
                              hipStream_t stream) {
    const float* x = (const float*)d_in[0];
    const int* ei = (const int*)d_in[1];       // int32 per harness contract
    const float* hc = (const float*)d_in[2];
    // d_in[3] = c_cur unused
    const float* W = (const float*)d_in[4];
    const float* b = (const float*)d_in[5];
    float* out = (float*)d_out;

    int n = in_sizes[0] / HID;      // 100000
    int E = in_sizes[1] / 2;        // 3200000
    int nbuck = (n + 63) >> BSH;    // 1563 (<= MAXBUCK)
    int nsb = 256;                  // binscatter blocks in fused phase3

    // workspace layout (16B-aligned), total ~38.9 MB
    char* ws = (char*)d_ws;
    unsigned* bcount = (unsigned*)(ws);                    // 8KB region
    unsigned* boff   = (unsigned*)(ws + 8192);             // 8KB region (nbuck+1)
    unsigned* bwoff  = (unsigned*)(ws + 16384);            // 8KB region
    float*    dinv   = (float*)   (ws + 24576);            // n*4 = 400000
    unsigned* binned = (unsigned*)(ws + 424576);           // E*4 = 12.8MB
    unsigned short* hp = (unsigned short*)(ws + 13224576); // [n][128] bf16 = 25.6MB

    zero_kernel<<<(nbuck + 255) / 256, 256, 0, stream>>>(bcount, nbuck);
    bincount_kernel<<<512, 256, 0, stream>>>(ei, bcount, E, n, nbuck);
    bscan_kernel<<<1, 1024, 0, stream>>>(bcount, boff, bwoff, nbuck);

    int gemm_blocks = (n + 63) / 64;   // 1563
    phase3_kernel<<<nsb + gemm_blocks, 256, 0, stream>>>(ei, bwoff, binned, x, hc, W, hp,
                                                         E, n, nbuck, nsb);
    degree_kernel<<<nbuck, 256, 0, stream>>>(binned, boff, dinv, n);
    agg_direct_kernel<<<nbuck, 256, 0, stream>>>(binned, boff, dinv, hp, b, out, n);
}

// Round 11
// 241.883 us; speedup vs baseline: 10.2179x; 10.2179x over previous
//
#include <hip/hip_runtime.h>
#include <hip/hip_bf16.h>

#define HID 128
#define BSH 6            // 64 nodes per bucket
#define MAXBUCK 2048     // >= ceil(n/64); n=100000 -> 1563
#define CAP 2816         // per-bucket LDS edge capacity (mean 2048, sigma~45)

__device__ __forceinline__ float b2f(unsigned short u) {
    union { unsigned i; float f; } v; v.i = ((unsigned)u) << 16; return v.f;
}
__device__ __forceinline__ unsigned short f2b(float f) {
    unsigned u = __float_as_uint(f);
    return (unsigned short)((u + 0x7fffu + ((u >> 16) & 1u)) >> 16);  // RNE
}

// ---------------- zero bucket counters ----------------
__global__ void zero_kernel(unsigned* __restrict__ p, int n) {
    int i = blockIdx.x * blockDim.x + threadIdx.x;
    if (i < n) p[i] = 0u;
}

// ---------------- K1: bucket histogram (LDS-aggregated) ----------------
__global__ __launch_bounds__(256) void bincount_kernel(const int* __restrict__ ei,
                                                       unsigned* __restrict__ bcount,
                                                       int E, int n, int nbuck) {
    __shared__ unsigned hist[MAXBUCK];
    for (int i = threadIdx.x; i < nbuck; i += 256) hist[i] = 0u;
    __syncthreads();
    int i = blockIdx.x * 256 + threadIdx.x, stride = gridDim.x * 256;
    for (; i < E; i += stride) {
        int dst = ei[(size_t)E + i];
        if ((unsigned)dst < (unsigned)n) atomicAdd(&hist[dst >> BSH], 1u);
    }
    __syncthreads();
    for (int b = threadIdx.x; b < nbuck; b += 256) {
        unsigned c = hist[b];
        if (c) atomicAdd(&bcount[b], c);
    }
}

// ---------------- K2: scan of bucket counts (single block) ----------------
__global__ __launch_bounds__(1024) void bscan_kernel(const unsigned* __restrict__ bcount,
                                                     unsigned* __restrict__ boff,
                                                     unsigned* __restrict__ bwoff,
                                                     int nbuck) {
    __shared__ unsigned sums[1024];
    int t = threadIdx.x;
    int chunk = (nbuck + 1023) >> 10;
    int beg = min(t * chunk, nbuck), end = min(beg + chunk, nbuck);
    unsigned local = 0;
    for (int i = beg; i < end; ++i) local += bcount[i];
    sums[t] = local;
    __syncthreads();
    for (int d = 1; d < 1024; d <<= 1) {
        unsigned v = (t >= d) ? sums[t - d] : 0u;
        __syncthreads();
        sums[t] += v;
        __syncthreads();
    }
    unsigned run = (t > 0) ? sums[t - 1] : 0u;
    for (int i = beg; i < end; ++i) { boff[i] = run; bwoff[i] = run; run += bcount[i]; }
    if (t == 1023) boff[nbuck] = sums[1023];
}

// ---------------- K3 (fused): binscatter (blocks 0..nsb-1) + gemm (rest) ----------------
// binned[pos] = (dst&63)<<20 | src ; gemm: hp = (x+h_cur)@W[:,0:128] bf16 flat [n][128]
__global__ __launch_bounds__(256) void phase3_kernel(const int* __restrict__ ei,
                                                     unsigned* __restrict__ bwoff,
                                                     unsigned* __restrict__ binned,
                                                     const float* __restrict__ x,
                                                     const float* __restrict__ hc,
                                                     const float* __restrict__ W,
                                                     unsigned short* __restrict__ hp,
                                                     int E, int n, int nbuck, int nsb) {
    __shared__ union {
        struct { unsigned hist[MAXBUCK]; unsigned base[MAXBUCK]; } bs;
        float A[64 * 132];
    } sm;

    if (blockIdx.x < nsb) {
        // ---- binscatter body ----
        int chunk = (E + nsb - 1) / nsb;
        int beg = blockIdx.x * chunk, end = min(E, beg + chunk);
        for (int i = threadIdx.x; i < nbuck; i += 256) sm.bs.hist[i] = 0u;
        __syncthreads();
        for (int i = beg + threadIdx.x; i < end; i += 256) {
            int dst = ei[(size_t)E + i];
            if ((unsigned)dst < (unsigned)n) atomicAdd(&sm.bs.hist[dst >> BSH], 1u);
        }
        __syncthreads();
        for (int b = threadIdx.x; b < nbuck; b += 256) {
            unsigned c = sm.bs.hist[b];
            sm.bs.base[b] = c ? atomicAdd(&bwoff[b], c) : 0u;
            sm.bs.hist[b] = 0u;
        }
        __syncthreads();
        for (int i = beg + threadIdx.x; i < end; i += 256) {
            int s = ei[i];
            int dst = ei[(size_t)E + i];
            if ((unsigned)dst >= (unsigned)n) continue;
            unsigned ss = (unsigned)min(max(s, 0), n - 1);
            int b = dst >> BSH;
            unsigned r = atomicAdd(&sm.bs.hist[b], 1u);
            binned[sm.bs.base[b] + r] = ss | ((unsigned)(dst & ((1 << BSH) - 1)) << 20);
        }
    } else {
        // ---- gemm body, flat hp output (unscaled) ----
        int tid = threadIdx.x;
        int r0 = (blockIdx.x - nsb) * 64;

        for (int i = tid; i < 2048; i += 256) {
            int row = i >> 5;
            int c4 = (i & 31) * 4;
            int grow = r0 + row;
            float4 v;
            if (grow < n) {
                float4 a = *(const float4*)(x + (size_t)grow * HID + c4);
                float4 bb = *(const float4*)(hc + (size_t)grow * HID + c4);
                v = make_float4(a.x + bb.x, a.y + bb.y, a.z + bb.z, a.w + bb.w);
            } else {
                v = make_float4(0.f, 0.f, 0.f, 0.f);
            }
            *(float4*)(&sm.A[row * 132 + c4]) = v;
        }
        __syncthreads();

        int cg = tid & 31;
        int c4 = cg * 4;
        int rg = tid >> 5;
        float acc[8][4];
#pragma unroll
        for (int r = 0; r < 8; ++r) {
            acc[r][0] = 0.f; acc[r][1] = 0.f; acc[r][2] = 0.f; acc[r][3] = 0.f;
        }

#pragma unroll 4
        for (int k = 0; k < 128; ++k) {
            float4 w = *(const float4*)(W + (size_t)k * 512 + c4);
#pragma unroll
            for (int r = 0; r < 8; ++r) {
                float a = sm.A[(rg * 8 + r) * 132 + k];
                acc[r][0] += a * w.x;
                acc[r][1] += a * w.y;
                acc[r][2] += a * w.z;
                acc[r][3] += a * w.w;
            }
        }

#pragma unroll
        for (int r = 0; r < 8; ++r) {
            int grow = r0 + rg * 8 + r;
            if (grow < n) {
                unsigned long long pack =
                    (unsigned long long)f2b(acc[r][0]) |
                    ((unsigned long long)f2b(acc[r][1]) << 16) |
                    ((unsigned long long)f2b(acc[r][2]) << 32) |
                    ((unsigned long long)f2b(acc[r][3]) << 48);
                *(unsigned long long*)(hp + (size_t)grow * HID + c4) = pack;
            }
        }
    }
}

// ---------------- K4: per-bucket degree -> off[node], dinv[node] (no placement) ----------------
__global__ __launch_bounds__(256) void csrlite_kernel(const unsigned* __restrict__ binned,
                                                      const unsigned* __restrict__ boff,
                                                      unsigned* __restrict__ off,
                                                      float* __restrict__ dinv, int n) {
    __shared__ unsigned hist[64];
    int b = blockIdx.x;
    int t = threadIdx.x;
    if (t < 64) hist[t] = 0u;
    __syncthreads();
    unsigned s0 = boff[b], s1 = boff[b + 1];
    for (unsigned j = s0 + t; j < s1; j += 256) atomicAdd(&hist[binned[j] >> 20], 1u);
    __syncthreads();
    if (t < 64) {
        unsigned cnt = hist[t];
        unsigned x = cnt;
        for (int d = 1; d < 64; d <<= 1) {
            unsigned v = __shfl_up(x, d, 64);
            if (t >= d) x += v;
        }
        unsigned excl = x - cnt;
        int node = (b << BSH) + t;
        if (node < n) {
            off[node] = s0 + excl;
            dinv[node] = rsqrtf((float)(cnt + 1u));  // +1 self-loop
        }
    }
}

// ---------------- K5: merged placement + aggregate (one bucket per block) ----------------
// Single pass places 20-bit srcs into LDS (uint cursor atomics), then r7-style
// atomic-free per-node gather: wave = one node at a time, 2 cols/lane, 8-deep MLP.
__global__ __launch_bounds__(256) void agg_merged_kernel(const unsigned* __restrict__ binned,
                                                         const unsigned* __restrict__ boff,
                                                         const unsigned* __restrict__ off,
                                                         const float* __restrict__ dinv,
                                                         const unsigned short* __restrict__ hp,
                                                         const float* __restrict__ bias,
                                                         float* __restrict__ out, int n) {
    __shared__ unsigned srcs_lds[CAP];
    __shared__ unsigned nodeoff[65];
    __shared__ unsigned cursor[64];
    __shared__ float sdinv[64];
    int b = blockIdx.x;
    int tid = threadIdx.x;
    unsigned s0 = boff[b], s1 = boff[b + 1];
    unsigned cnt = s1 - s0;
    int node0 = b << BSH;

    if (tid < 64) {
        int node = node0 + tid;
        unsigned o = (node < n) ? off[node] : s1;
        nodeoff[tid] = o - s0;
        cursor[tid] = o - s0;
        sdinv[tid] = (node < n) ? dinv[node] : 0.f;
    }
    if (tid == 64) nodeoff[64] = cnt;
    __syncthreads();

    if (cnt <= CAP) {
        // placement pass: binned -> LDS per-node lists
        for (unsigned j = s0 + tid; j < s1; j += 256) {
            unsigned p = binned[j];
            unsigned slot = atomicAdd(&cursor[p >> 20], 1u);
            srcs_lds[slot] = p & 0xFFFFFu;
        }
        __syncthreads();

        int w = tid >> 6, lane = tid & 63;
        int c = lane * 2;
        for (int nl = w * 16; nl < w * 16 + 16; ++nl) {
            int node = node0 + nl;
            if (node >= n) break;
            unsigned beg = nodeoff[nl], end2 = nodeoff[nl + 1];
            float ax = 0.f, ay = 0.f;
            unsigned i = beg;
            for (; i + 8 <= end2; i += 8) {
                unsigned s[8]; float wd[8]; ushort2 v[8];
#pragma unroll
                for (int j = 0; j < 8; ++j) s[j] = srcs_lds[i + j];
#pragma unroll
                for (int j = 0; j < 8; ++j) wd[j] = dinv[s[j]];
#pragma unroll
                for (int j = 0; j < 8; ++j) v[j] = *(const ushort2*)(hp + ((size_t)s[j] << 7) + c);
#pragma unroll
                for (int j = 0; j < 8; ++j) { ax += wd[j] * b2f(v[j].x); ay += wd[j] * b2f(v[j].y); }
            }
            if (i < end2) {  // masked clamped tail, keeps 8 loads in flight
                unsigned last = end2 - 1;
                unsigned s[8]; float wd[8]; ushort2 v[8];
#pragma unroll
                for (int j = 0; j < 8; ++j) {
                    unsigned jj = i + j;
                    s[j] = srcs_lds[jj < end2 ? jj : last];
                    wd[j] = (jj < end2) ? 1.f : 0.f;
                }
#pragma unroll
                for (int j = 0; j < 8; ++j) wd[j] *= dinv[s[j]];
#pragma unroll
                for (int j = 0; j < 8; ++j) v[j] = *(const ushort2*)(hp + ((size_t)s[j] << 7) + c);
#pragma unroll
                for (int j = 0; j < 8; ++j) { ax += wd[j] * b2f(v[j].x); ay += wd[j] * b2f(v[j].y); }
            }
            // self-loop + scale + bias
            float dd = sdinv[nl];
            ushort2 hd = *(const ushort2*)(hp + ((size_t)node << 7) + c);
            ax += dd * b2f(hd.x);
            ay += dd * b2f(hd.y);
            float2 bb = *(const float2*)(bias + c);
            float2 res = make_float2(dd * ax + bb.x, dd * ay + bb.y);
            *(float2*)(out + ((size_t)node << 7) + c) = res;
        }
    } else {
        // correctness-only fallback (never triggers for this data): init then serial edges
        for (int idx = tid; idx < 64 * HID; idx += 256) {
            int ndl = idx >> 7, col = idx & (HID - 1);
            int node = node0 + ndl;
            if (node < n) {
                float dd = sdinv[ndl];
                out[((size_t)node << 7) + col] = dd * dd * b2f(hp[((size_t)node << 7) + col]) + bias[col];
            }
        }
        __syncthreads();
        if (tid < 64) {  // wave 0 only: lockstep, disjoint cols -> no race
            int c = tid * 2;
            for (unsigned j = s0; j < s1; ++j) {
                unsigned p = binned[j];
                unsigned dl = p >> 20, s = p & 0xFFFFFu;
                float wsc = dinv[s] * sdinv[dl];
                ushort2 v = *(const ushort2*)(hp + ((size_t)s << 7) + c);
                float2* o = (float2*)(out + ((size_t)(node0 + dl) << 7) + c);
                float2 cur = *o;
                cur.x += wsc * b2f(v.x);
                cur.y += wsc * b2f(v.y);
                *o = cur;
            }
        }
    }
}

extern "C" void kernel_launch(void* const* d_in, const int* in_sizes, int n_in,
                              void* d_out, int out_size, void* d_ws, size_t ws_size,
                              hipStream_t stream) {
    const float* x = (const float*)d_in[0];
    const int* ei = (const int*)d_in[1];       // int32 per harness contract
    const float* hc = (const float*)d_in[2];
    // d_in[3] = c_cur unused
    const float* W = (const float*)d_in[4];
    const float* b = (const float*)d_in[5];
    float* out = (float*)d_out;

    int n = in_sizes[0] / HID;      // 100000
    int E = in_sizes[1] / 2;        // 3200000
    int nbuck = (n + 63) >> BSH;    // 1563 (<= MAXBUCK)
    int nsb = 256;                  // binscatter blocks in fused phase3

    // workspace layout (16B-aligned), total ~39.2 MB
    char* ws = (char*)d_ws;
    unsigned* bcount = (unsigned*)(ws);                    // 8KB region
    unsigned* boff   = (unsigned*)(ws + 8192);             // 8KB region (nbuck+1)
    unsigned* bwoff  = (unsigned*)(ws + 16384);            // 8KB region
    unsigned* off    = (unsigned*)(ws + 24576);            // n*4 = 400000
    float*    dinv   = (float*)   (ws + 424576);           // n*4
    unsigned* binned = (unsigned*)(ws + 824576);           // E*4 = 12.8MB
    unsigned short* hp = (unsigned short*)(ws + 13624576); // [n][128] bf16 = 25.6MB

    zero_kernel<<<(nbuck + 255) / 256, 256, 0, stream>>>(bcount, nbuck);
    bincount_kernel<<<512, 256, 0, stream>>>(ei, bcount, E, n, nbuck);
    bscan_kernel<<<1, 1024, 0, stream>>>(bcount, boff, bwoff, nbuck);

    int gemm_blocks = (n + 63) / 64;   // 1563
    phase3_kernel<<<nsb + gemm_blocks, 256, 0, stream>>>(ei, bwoff, binned, x, hc, W, hp,
                                                         E, n, nbuck, nsb);
    csrlite_kernel<<<nbuck, 256, 0, stream>>>(binned, boff, off, dinv, n);
    agg_merged_kernel<<<nbuck, 256, 0, stream>>>(binned, boff, off, dinv, hp, b, out, n);
}